// Round 7
// baseline (236.756 us; speedup 1.0000x reference)
//
#include <hip/hip_runtime.h>
#include <math.h>

#define N_NODES 50000
#define N_EDGES 800000
#define IN_DIM  256
#define F1      128   // HEADS*HID
#define HEADS   4
#define OUT_DIM 40
#define NEG     0.2f

// CSR bucket sort params
#define NB   391     // buckets of 128 nodes: 50000/128 -> 391
#define CAP  3072    // per-bucket capacity (mean 2048, sigma ~45 -> >20 sigma margin)
#define EB   2048    // edges per bin block (R7: halved -> 2x bin blocks, 1.6/CU)
#define PREW 16      // w1pack blocks inside pre_kernel
#define G1B  782     // gemm1 blocks inside mid_kernel: (N_NODES+63)/64

typedef __attribute__((ext_vector_type(8))) short short8;    // 8 bf16 in 4 VGPRs
typedef __attribute__((ext_vector_type(4))) float float4v;   // MFMA C/D

// ---- bf16 helpers (RNE pack, shift unpack) ----
__device__ __forceinline__ unsigned short f2bf(float f) {
  unsigned int u = __float_as_uint(f);
  u += 0x7FFF + ((u >> 16) & 1);
  return (unsigned short)(u >> 16);
}
__device__ __forceinline__ float bf2f(unsigned short h) {
  return __uint_as_float((unsigned int)h << 16);
}
__device__ __forceinline__ float bflo(unsigned int u) { return __uint_as_float(u << 16); }
__device__ __forceinline__ float bfhi(unsigned int u) { return __uint_as_float(u & 0xffff0000u); }

__device__ __forceinline__ float lrelu(float e) { return e > 0.f ? e : e * NEG; }

// async global->LDS DMA, 16B per lane. LDS dest must be wave-uniform base
// (HW adds lane*16); global src is per-lane.
__device__ __forceinline__ void gload_lds16(const void* g, void* l) {
  __builtin_amdgcn_global_load_lds(
      (const __attribute__((address_space(1))) unsigned int*)g,
      (__attribute__((address_space(3))) unsigned int*)l, 16, 0, 0);
}

// ---------------- pre_kernel: w1pack (blocks 0..15) U bin (blocks 16..406) ----------------
__global__ __launch_bounds__(256) void pre_kernel(const float* __restrict__ W1,
                                                  unsigned short* __restrict__ wHi,
                                                  unsigned short* __restrict__ wLo,
                                                  const int* __restrict__ ei,
                                                  int* __restrict__ gcnt,
                                                  int2* __restrict__ gbucket) {
  __shared__ int smem[EB * 2 + NB * 3];   // 21 KB arena (bin role)
  if (blockIdx.x < PREW) {
    // ---- w1pack role: W1 -> MFMA B-fragment packing (hi/lo split) ----
    int tid = blockIdx.x * 256 + threadIdx.x;   // 0..4095
    int kk = tid >> 9;
    int rest = tid & 511;
    int t = rest >> 6;
    int lane = rest & 63;
    int q = lane >> 4;
    int ln = lane & 15;
    int n = t * 16 + ln;
    unsigned int hi[4], lo[4];
#pragma unroll
    for (int jj = 0; jj < 4; jj++) {
      unsigned short h0, h1, l0, l1;
      {
        float v = W1[(kk * 32 + q * 8 + jj * 2) * F1 + n];
        h0 = f2bf(v); l0 = f2bf(v - bf2f(h0));
      }
      {
        float v = W1[(kk * 32 + q * 8 + jj * 2 + 1) * F1 + n];
        h1 = f2bf(v); l1 = f2bf(v - bf2f(h1));
      }
      hi[jj] = (unsigned int)h0 | ((unsigned int)h1 << 16);
      lo[jj] = (unsigned int)l0 | ((unsigned int)l1 << 16);
    }
    size_t base = (size_t)tid * 8;
    *(uint4*)&wHi[base] = make_uint4(hi[0], hi[1], hi[2], hi[3]);
    *(uint4*)&wLo[base] = make_uint4(lo[0], lo[1], lo[2], lo[3]);
  } else {
    // ---- bin role: bucketed counting sort (line-local writes) ----
    int* ls = smem;
    int* ld = smem + EB;
    int* lcnt = smem + 2 * EB;
    int* lcur = lcnt + NB;
    int* gbaseS = lcur + NB;
    int tid = threadIdx.x;
    size_t base = (size_t)(blockIdx.x - PREW) * EB;
    for (int t = tid; t < NB; t += 256) { lcnt[t] = 0; lcur[t] = 0; }
    __syncthreads();
#pragma unroll
    for (int l = 0; l < EB / 256; l++) {
      int li = l * 256 + tid;
      size_t idx = base + li;
      int s = 0, d = -1;
      if (idx < N_EDGES) {
        s = ei[idx];
        d = ei[N_EDGES + idx];
        atomicAdd(&lcnt[d >> 7], 1);
      }
      ls[li] = s;
      ld[li] = d;
    }
    __syncthreads();
    for (int t = tid; t < NB; t += 256) gbaseS[t] = atomicAdd(&gcnt[t], lcnt[t]);
    __syncthreads();
#pragma unroll
    for (int l = 0; l < EB / 256; l++) {
      int li = l * 256 + tid;
      int d = ld[li];
      if (d >= 0) {
        int b = d >> 7;
        int r = gbaseS[b] + atomicAdd(&lcur[b], 1);
        if (r >= CAP) r = CAP - 1;   // overflow guard (statistically impossible)
        gbucket[(size_t)b * CAP + r] = make_int2(ls[li], d);
      }
    }
  }
}

// ---------------- mid_kernel: gemm1 (blocks 0..781, 8 waves) U csr (blocks 782..1172) ----
// R7: gemm1 role goes 512-thread/8-wave with a column split (waves 0-3 cols 0-63,
// waves 4-7 cols 64-127). Wave count 3128 -> 6256 (38% -> 76% of machine cap);
// per-wave MFMA work halves, acc VGPRs 32 -> 16. B staging per block unchanged.
// Same MFMA sequence per output tile -> bit-identical results.
__global__ __launch_bounds__(512, 6) void mid_kernel(
    const float* __restrict__ x, const unsigned short* __restrict__ wHi,
    const unsigned short* __restrict__ wLo,
    const float* __restrict__ a_src, const float* __restrict__ a_dst,
    unsigned short* __restrict__ h1b, float* __restrict__ as1, float* __restrict__ ad1,
    const int2* __restrict__ gbucket, const int* __restrict__ gcnt,
    int* __restrict__ row_ptr, int* __restrict__ col) {
  __shared__ short8 smem[2048];   // 32 KB arena, 16B aligned
  if (blockIdx.x < G1B) {
    // ================= gemm1 role =================
    short8 (*Bsh)[1024] = (short8(*)[1024])smem;  // [buf][0..511]=hi, [512..1023]=lo
    int bid = blockIdx.x;
    int tid = threadIdx.x;
    int w = tid >> 6;        // 0..7
    int lane = tid & 63;
    int ch = w >> 2;         // column half: 0 -> cols 0..63, 1 -> cols 64..127
    int w4 = w & 3;          // row group
    int q = lane >> 4;
    int ln = lane & 15;
    int rowBase = bid * 64 + w4 * 16;
    int rowA = rowBase + ln;
    int rowAc = rowA < N_NODES ? rowA : N_NODES - 1;
    float4v acc[4];
#pragma unroll
    for (int t = 0; t < 4; t++) acc[t] = (float4v){0.f, 0.f, 0.f, 0.f};
    const short8* bhp = (const short8*)wHi;
    const short8* blp = (const short8*)wLo;

    // stage slab kk into Bsh[buf]: 1024 x 16B = 16KB; 8 waves x 2 gloads
    auto prefetch = [&](int kk, int buf) {
      int chunk = w;   // 0..7, 64 elements each
      gload_lds16(bhp + (size_t)kk * 512 + chunk * 64 + lane, &Bsh[buf][chunk * 64]);
      gload_lds16(blp + (size_t)kk * 512 + chunk * 64 + lane, &Bsh[buf][512 + chunk * 64]);
    };

    const float4* xbase = (const float4*)(x + (size_t)rowAc * IN_DIM + q * 8);
    float4 a0 = xbase[0];
    float4 a1 = xbase[1];
    prefetch(0, 0);
    __syncthreads();   // drains vmcnt: slab 0 + a0/a1 resident

#pragma unroll 1
    for (int kk = 0; kk < 8; kk++) {
      int buf = kk & 1;
      if (kk < 7) prefetch(kk + 1, buf ^ 1);   // overlaps with compute below
      int kn = (kk < 7) ? kk + 1 : 7;
      float4 n0 = xbase[kn * 8];
      float4 n1 = xbase[kn * 8 + 1];
      float av[8] = {a0.x, a0.y, a0.z, a0.w, a1.x, a1.y, a1.z, a1.w};
      short8 ahi, alo;
#pragma unroll
      for (int j = 0; j < 8; j++) {
        unsigned short hh = f2bf(av[j]);
        ahi[j] = (short)hh;
        alo[j] = (short)f2bf(av[j] - bf2f(hh));
      }
      const short8* bs = &Bsh[buf][0];
#pragma unroll
      for (int t = 0; t < 4; t++) {
        int te = ch * 4 + t;
        short8 bh = bs[te * 64 + lane];
        short8 bl = bs[512 + te * 64 + lane];
        acc[t] = __builtin_amdgcn_mfma_f32_16x16x32_bf16(ahi, bh, acc[t], 0, 0, 0);
        acc[t] = __builtin_amdgcn_mfma_f32_16x16x32_bf16(ahi, bl, acc[t], 0, 0, 0);
        acc[t] = __builtin_amdgcn_mfma_f32_16x16x32_bf16(alo, bh, acc[t], 0, 0, 0);
      }
      a0 = n0;
      a1 = n1;
      if (kk < 7) __syncthreads();
    }

    float asv[4], adv[4];
#pragma unroll
    for (int t = 0; t < 4; t++) {
      asv[t] = a_src[(ch * 4 + t) * 16 + ln];
      adv[t] = a_dst[(ch * 4 + t) * 16 + ln];
    }
#pragma unroll
    for (int reg = 0; reg < 4; reg++) {
      int r = rowBase + q * 4 + reg;
      bool valid = (r < N_NODES);
      if (valid) {
#pragma unroll
        for (int t = 0; t < 4; t++)
          h1b[(size_t)r * F1 + (ch * 4 + t) * 16 + ln] = f2bf(acc[t][reg]);
      }
#pragma unroll
      for (int hh = 0; hh < 2; hh++) {   // head = ch*2 + hh
        float sa = acc[2 * hh][reg] * asv[2 * hh] + acc[2 * hh + 1][reg] * asv[2 * hh + 1];
        float sd = acc[2 * hh][reg] * adv[2 * hh] + acc[2 * hh + 1][reg] * adv[2 * hh + 1];
#pragma unroll
        for (int off = 1; off < 16; off <<= 1) {
          sa += __shfl_xor(sa, off);
          sd += __shfl_xor(sd, off);
        }
        if (ln == 0 && valid) {
          as1[r * 4 + ch * 2 + hh] = sa;
          ad1[r * 4 + ch * 2 + hh] = sd;
        }
      }
    }
  } else {
    // ================= csr role (512-thread strides) =============
    int2* ent = (int2*)smem;                 // CAP * 8 = 24576 B
    int* hcnt = (int*)(ent + CAP);           // 512 B
    int* sc   = hcnt + 128;                  // 512 B
    int* cur  = sc + 128;                    // 512 B
    int* red  = cur + 128;                   // 32 B (8 wave partials)
    int b = blockIdx.x - G1B;
    int tid = threadIdx.x;
    int cnt = gcnt[b]; if (cnt > CAP) cnt = CAP;
    if (tid < 128) hcnt[tid] = 0;
    // base = sum(gcnt[0..b-1]) : strided read + wave reduce + cross-wave via LDS
    int part = 0;
    for (int i = tid; i < b; i += 512) part += gcnt[i];
#pragma unroll
    for (int off = 32; off > 0; off >>= 1) part += __shfl_xor(part, off);
    if ((tid & 63) == 0) red[tid >> 6] = part;
    __syncthreads();
    int base = red[0] + red[1] + red[2] + red[3] + red[4] + red[5] + red[6] + red[7];
    for (int i = tid; i < cnt; i += 512) {
      int2 e = gbucket[(size_t)b * CAP + i];
      ent[i] = e;
      atomicAdd(&hcnt[e.y & 127], 1);
    }
    __syncthreads();
    if (tid < 128) sc[tid] = hcnt[tid];
    __syncthreads();
    for (int off = 1; off < 128; off <<= 1) {
      int t = 0;
      if (tid < 128 && tid >= off) t = sc[tid - off];
      __syncthreads();
      if (tid < 128) sc[tid] += t;
      __syncthreads();
    }
    if (tid < 128) {
      int excl = sc[tid] - hcnt[tid];
      cur[tid] = excl;
      int node = (b << 7) + tid;
      if (node < N_NODES) row_ptr[node] = base + excl;
    }
    if (b == 0 && tid == 0) row_ptr[N_NODES] = N_EDGES;
    __syncthreads();
    for (int i = tid; i < cnt; i += 512) {
      int2 e = ent[i];
      int r = atomicAdd(&cur[e.y & 127], 1);
      col[base + r] = e.x;
    }
  }
}

// ---------------- layer-1: single-pass gather (R4) ----------------
// alpha = e/sum(e) commutes with accumulation: out = (sum e*h)/(sum e).
// Keep this kernel lean: low VGPR + high occupancy IS its performance (R5 lesson).
__global__ __launch_bounds__(256) void gather1_kernel(
    const unsigned short* __restrict__ h1b, const float* __restrict__ as1,
    const float* __restrict__ ad1, const float* __restrict__ b1,
    const int* __restrict__ row_ptr, const int* __restrict__ col,
    float* __restrict__ x2) {
  int wv = threadIdx.x >> 6;
  int n = blockIdx.x * 4 + wv;
  if (n >= N_NODES) return;
  int lane = threadIdx.x & 63;
  int start = row_ptr[n];
  int deg = row_ptr[n + 1] - start;
  int slot = lane >> 4;
  int lane16 = lane & 15;
  int head = lane16 >> 2;
  float adh = ad1[n * 4 + head];
  float4 accA = make_float4(0.f, 0.f, 0.f, 0.f);
  float4 accB = make_float4(0.f, 0.f, 0.f, 0.f);
  float dn = 0.f;
  int i = slot;
  for (; i + 4 <= deg; i += 8) {   // unroll 2: two independent edge chains in flight
    int sA = col[start + i];
    int sB = (i + 4 < deg) ? col[start + i + 4] : n;   // i+4==deg -> self loop
    float eA = __expf(lrelu(as1[sA * 4 + head] + adh));
    float eB = __expf(lrelu(as1[sB * 4 + head] + adh));
    uint4 uA = *(const uint4*)(h1b + (size_t)sA * F1 + lane16 * 8);
    uint4 uB = *(const uint4*)(h1b + (size_t)sB * F1 + lane16 * 8);
    dn += eA + eB;
    accA.x += eA * bflo(uA.x); accA.y += eA * bfhi(uA.x);
    accA.z += eA * bflo(uA.y); accA.w += eA * bfhi(uA.y);
    accB.x += eA * bflo(uA.z); accB.y += eA * bfhi(uA.z);
    accB.z += eA * bflo(uA.w); accB.w += eA * bfhi(uA.w);
    accA.x += eB * bflo(uB.x); accA.y += eB * bfhi(uB.x);
    accA.z += eB * bflo(uB.y); accA.w += eB * bfhi(uB.y);
    accB.x += eB * bflo(uB.z); accB.y += eB * bfhi(uB.z);
    accB.z += eB * bflo(uB.w); accB.w += eB * bfhi(uB.w);
  }
  if (i <= deg) {   // at most one remaining edge per slot (i+4 > deg)
    int s = (i < deg) ? col[start + i] : n;
    float e = __expf(lrelu(as1[s * 4 + head] + adh));
    uint4 u = *(const uint4*)(h1b + (size_t)s * F1 + lane16 * 8);
    dn += e;
    accA.x += e * bflo(u.x); accA.y += e * bfhi(u.x);
    accA.z += e * bflo(u.y); accA.w += e * bfhi(u.y);
    accB.x += e * bflo(u.z); accB.y += e * bfhi(u.z);
    accB.z += e * bflo(u.w); accB.w += e * bfhi(u.w);
  }
  // cross-slot reduce: slot bits are lane bits 4,5 (xor butterfly); dn is 9th value
#pragma unroll
  for (int off = 16; off <= 32; off <<= 1) {
    accA.x += __shfl_xor(accA.x, off); accA.y += __shfl_xor(accA.y, off);
    accA.z += __shfl_xor(accA.z, off); accA.w += __shfl_xor(accA.w, off);
    accB.x += __shfl_xor(accB.x, off); accB.y += __shfl_xor(accB.y, off);
    accB.z += __shfl_xor(accB.z, off); accB.w += __shfl_xor(accB.w, off);
    dn += __shfl_xor(dn, off);
  }
  if (slot == 0) {
    float rsh = 1.f / (dn + 1e-16f);
    float4 bA = *(const float4*)&b1[lane16 * 8];
    float4 bB = *(const float4*)&b1[lane16 * 8 + 4];
    float4 oA, oB;
    oA.x = fmaxf(accA.x * rsh + bA.x, 0.f); oA.y = fmaxf(accA.y * rsh + bA.y, 0.f);
    oA.z = fmaxf(accA.z * rsh + bA.z, 0.f); oA.w = fmaxf(accA.w * rsh + bA.w, 0.f);
    oB.x = fmaxf(accB.x * rsh + bB.x, 0.f); oB.y = fmaxf(accB.y * rsh + bB.y, 0.f);
    oB.z = fmaxf(accB.z * rsh + bB.z, 0.f); oB.w = fmaxf(accB.w * rsh + bB.w, 0.f);
    *(float4*)&x2[(size_t)n * F1 + lane16 * 8] = oA;
    *(float4*)&x2[(size_t)n * F1 + lane16 * 8 + 4] = oB;
  }
}

// ---------------- GEMM2 tiled + alpha2 fused: h2b = x2@W2 (bf16), as2/ad2 ----------------
__global__ __launch_bounds__(256) void gemm2_kernel(
    const float* __restrict__ x2, const float* __restrict__ W2,
    const float* __restrict__ asv, const float* __restrict__ adv,
    unsigned short* __restrict__ h2b, float* __restrict__ as2, float* __restrict__ ad2) {
  __shared__ float xs[64][132];
  __shared__ float W2s[128][44];
  __shared__ float asv_s[40], adv_s[40];
  int tid = threadIdx.x;
  int bm = blockIdx.x * 64;
#pragma unroll
  for (int l = 0; l < 8; l++) {
    int idx = tid + l * 256;
    int r = idx >> 5;
    int c4 = (idx & 31) << 2;
    float4 v = make_float4(0.f, 0.f, 0.f, 0.f);
    if (bm + r < N_NODES) v = *(const float4*)&x2[(size_t)(bm + r) * F1 + c4];
    *(float4*)&xs[r][c4] = v;
  }
#pragma unroll
  for (int l = 0; l < 5; l++) {
    int idx = tid + l * 256;
    int k = idx / 10;
    int c4 = (idx - k * 10) * 4;
    *(float4*)&W2s[k][c4] = *(const float4*)&W2[k * OUT_DIM + c4];
  }
  if (tid < OUT_DIM) { asv_s[tid] = asv[tid]; adv_s[tid] = adv[tid]; }
  __syncthreads();
  int r = tid >> 2;
  int cb = (tid & 3) * 10;
  float acc[10] = {0.f};
  for (int k = 0; k < F1; k++) {
    float xv = xs[r][k];
#pragma unroll
    for (int c = 0; c < 10; c++) acc[c] += xv * W2s[k][cb + c];
  }
  int grow = bm + r;
  float sa = 0.f, sd = 0.f;
#pragma unroll
  for (int c = 0; c < 10; c++) {
    sa += acc[c] * asv_s[cb + c];
    sd += acc[c] * adv_s[cb + c];
  }
#pragma unroll
  for (int off = 1; off < 4; off <<= 1) {
    sa += __shfl_xor(sa, off);
    sd += __shfl_xor(sd, off);
  }
  if (grow < N_NODES) {
#pragma unroll
    for (int c = 0; c < 10; c += 2) {
      unsigned int p = ((unsigned int)f2bf(acc[c + 1]) << 16) | f2bf(acc[c]);
      *(unsigned int*)&h2b[(size_t)grow * OUT_DIM + cb + c] = p;
    }
    if ((tid & 3) == 0) { as2[grow] = sa; ad2[grow] = sd; }
  }
}

// ---------------- layer-2: single-pass gather + log_softmax (R4) ----------------
__global__ __launch_bounds__(256) void gather2_kernel(
    const unsigned short* __restrict__ h2b, const float* __restrict__ as2,
    const float* __restrict__ ad2, const float* __restrict__ b2,
    const int* __restrict__ row_ptr, const int* __restrict__ col,
    float* __restrict__ out) {
  int wv = threadIdx.x >> 6;
  int n = blockIdx.x * 4 + wv;
  if (n >= N_NODES) return;
  int lane = threadIdx.x & 63;
  int start = row_ptr[n];
  int deg = row_ptr[n + 1] - start;
  float adh = ad2[n];
  // 12 slots x 5 lanes (16B bf16x8, row=80B); lanes 60..63 idle
  int slot = lane / 5;
  int c = lane - slot * 5;
  float4 accA = make_float4(0.f, 0.f, 0.f, 0.f);
  float4 accB = make_float4(0.f, 0.f, 0.f, 0.f);
  float dn = 0.f;
  if (slot < 12) {
    for (int i = slot; i <= deg; i += 12) {
      int src = (i < deg) ? col[start + i] : n;
      float e = __expf(lrelu(as2[src] + adh));
      uint4 u = *(const uint4*)(h2b + (size_t)src * OUT_DIM + c * 8);
      dn += e;
      accA.x += e * bflo(u.x); accA.y += e * bfhi(u.x);
      accA.z += e * bflo(u.y); accA.w += e * bfhi(u.y);
      accB.x += e * bflo(u.z); accB.y += e * bfhi(u.z);
      accB.z += e * bflo(u.w); accB.w += e * bfhi(u.w);
    }
  }
  // cross-slot reduce (12 slots); temps read before update; dn is v[8]
  float v[9] = {accA.x, accA.y, accA.z, accA.w, accB.x, accB.y, accB.z, accB.w, dn};
#pragma unroll
  for (int k = 0; k < 9; k++) v[k] += __shfl(v[k], lane + 30);
#pragma unroll
  for (int k = 0; k < 9; k++) v[k] += __shfl(v[k], lane + 15);
  {
    float t1[9], t2[9];
#pragma unroll
    for (int k = 0; k < 9; k++) t1[k] = __shfl(v[k], lane + 5);
#pragma unroll
    for (int k = 0; k < 9; k++) t2[k] = __shfl(v[k], lane + 10);
#pragma unroll
    for (int k = 0; k < 9; k++) v[k] += t1[k] + t2[k];
  }
  bool owner = (slot == 0);
  float vals[8];
  float lmax = -1e30f, lsum = 0.f;
  if (owner) {
    float rs = 1.f / (v[8] + 1e-16f);
#pragma unroll
    for (int k = 0; k < 8; k++) {
      vals[k] = v[k] * rs + b2[c * 8 + k];
      lmax = fmaxf(lmax, vals[k]);
    }
  }
  float gmax = lmax;
#pragma unroll
  for (int off = 32; off > 0; off >>= 1) gmax = fmaxf(gmax, __shfl_xor(gmax, off));
  if (owner) {
#pragma unroll
    for (int k = 0; k < 8; k++) lsum += __expf(vals[k] - gmax);
  }
#pragma unroll
  for (int off = 32; off > 0; off >>= 1) lsum += __shfl_xor(lsum, off);
  if (owner) {
    float lse = gmax + __logf(lsum);
    float4 oA = make_float4(vals[0] - lse, vals[1] - lse, vals[2] - lse, vals[3] - lse);
    float4 oB = make_float4(vals[4] - lse, vals[5] - lse, vals[6] - lse, vals[7] - lse);
    *(float4*)&out[(size_t)n * OUT_DIM + c * 8] = oA;
    *(float4*)&out[(size_t)n * OUT_DIM + c * 8 + 4] = oB;
  }
}

extern "C" void kernel_launch(void* const* d_in, const int* in_sizes, int n_in,
                              void* d_out, int out_size, void* d_ws, size_t ws_size,
                              hipStream_t stream) {
  const float* x      = (const float*)d_in[0];
  const int*   ei     = (const int*)d_in[1];
  const float* W1     = (const float*)d_in[2];
  const float* a_src1 = (const float*)d_in[3];
  const float* a_dst1 = (const float*)d_in[4];
  const float* b1     = (const float*)d_in[5];
  const float* W2     = (const float*)d_in[6];
  const float* a_src2 = (const float*)d_in[7];
  const float* a_dst2 = (const float*)d_in[8];
  const float* b2     = (const float*)d_in[9];
  float* out = (float*)d_out;

  char* ws = (char*)d_ws;
  size_t off = 0;
  auto alloc = [&](size_t bytes) -> void* {
    void* p = ws + off;
    off += (bytes + 255) & ~(size_t)255;
    return p;
  };
  unsigned short* h1b = (unsigned short*)alloc((size_t)N_NODES * F1 * 2);       // 12.8 MB
  unsigned short* h2b = (unsigned short*)alloc((size_t)N_NODES * OUT_DIM * 2);  // 4 MB
  unsigned short* wHi = (unsigned short*)alloc((size_t)IN_DIM * F1 * 2);        // 64 KB
  unsigned short* wLo = (unsigned short*)alloc((size_t)IN_DIM * F1 * 2);        // 64 KB
  float* as1    = (float*)alloc((size_t)N_NODES * HEADS * 4);
  float* ad1    = (float*)alloc((size_t)N_NODES * HEADS * 4);
  float* x2     = (float*)alloc((size_t)N_NODES * F1 * 4);
  float* as2    = (float*)alloc((size_t)N_NODES * 4);
  float* ad2    = (float*)alloc((size_t)N_NODES * 4);
  int* row_ptr  = (int*)alloc((size_t)(N_NODES + 1) * 4);
  int* col      = (int*)alloc((size_t)N_EDGES * 4);
  int* gcnt     = (int*)alloc((size_t)NB * 4);
  int2* gbucket = (int2*)alloc((size_t)NB * CAP * 8);                           // 9.6 MB

  hipMemsetAsync(gcnt, 0, (size_t)NB * 4, stream);
  // pre: w1pack (16 blocks) U bin (391 blocks)
  pre_kernel<<<PREW + (N_EDGES + EB - 1) / EB, 256, 0, stream>>>(W1, wHi, wLo, ei, gcnt, gbucket);
  // mid: gemm1 (782 blocks x 8 waves) U csr-with-inline-scan (391 blocks)
  mid_kernel<<<G1B + NB, 512, 0, stream>>>(x, wHi, wLo, a_src1, a_dst1, h1b, as1, ad1,
                                           gbucket, gcnt, row_ptr, col);
  gather1_kernel<<<(N_NODES + 3) / 4, 256, 0, stream>>>(h1b, as1, ad1, b1, row_ptr, col, x2);

  gemm2_kernel<<<(N_NODES + 63) / 64, 256, 0, stream>>>(x2, W2, a_src2, a_dst2, h2b, as2, ad2);
  gather2_kernel<<<(N_NODES + 3) / 4, 256, 0, stream>>>(h2b, as2, ad2, b2, row_ptr, col, out);
}

// Round 8
// 233.388 us; speedup vs baseline: 1.0144x; 1.0144x over previous
//
#include <hip/hip_runtime.h>
#include <math.h>

#define N_NODES 50000
#define N_EDGES 800000
#define IN_DIM  256
#define F1      128   // HEADS*HID
#define HEADS   4
#define OUT_DIM 40
#define NEG     0.2f

// CSR bucket sort params
#define NB   391     // buckets of 128 nodes: 50000/128 -> 391
#define CAP  3072    // per-bucket capacity (mean 2048, sigma ~45 -> >20 sigma margin)
#define EB   4096    // edges per bin block
#define PREW 16      // w1pack blocks inside pre_kernel
#define G1B  782     // gemm1 blocks inside mid_kernel: (N_NODES+63)/64

typedef __attribute__((ext_vector_type(8))) short short8;    // 8 bf16 in 4 VGPRs
typedef __attribute__((ext_vector_type(4))) float float4v;   // MFMA C/D

// ---- bf16 helpers (RNE pack, shift unpack) ----
__device__ __forceinline__ unsigned short f2bf(float f) {
  unsigned int u = __float_as_uint(f);
  u += 0x7FFF + ((u >> 16) & 1);
  return (unsigned short)(u >> 16);
}
__device__ __forceinline__ float bf2f(unsigned short h) {
  return __uint_as_float((unsigned int)h << 16);
}
__device__ __forceinline__ float bflo(unsigned int u) { return __uint_as_float(u << 16); }
__device__ __forceinline__ float bfhi(unsigned int u) { return __uint_as_float(u & 0xffff0000u); }

__device__ __forceinline__ float lrelu(float e) { return e > 0.f ? e : e * NEG; }

// async global->LDS DMA, 16B per lane. LDS dest must be wave-uniform base
// (HW adds lane*16); global src is per-lane.
__device__ __forceinline__ void gload_lds16(const void* g, void* l) {
  __builtin_amdgcn_global_load_lds(
      (const __attribute__((address_space(1))) unsigned int*)g,
      (__attribute__((address_space(3))) unsigned int*)l, 16, 0, 0);
}

// ---------------- pre_kernel: w1pack (blocks 0..15) U bin (blocks 16..211) ----------------
__global__ __launch_bounds__(256) void pre_kernel(const float* __restrict__ W1,
                                                  unsigned short* __restrict__ wHi,
                                                  unsigned short* __restrict__ wLo,
                                                  const int* __restrict__ ei,
                                                  int* __restrict__ gcnt,
                                                  int2* __restrict__ gbucket) {
  __shared__ int smem[EB * 2 + NB * 3];   // 37.5 KB arena (bin role)
  if (blockIdx.x < PREW) {
    // ---- w1pack role: W1 -> MFMA B-fragment packing (hi/lo split) ----
    int tid = blockIdx.x * 256 + threadIdx.x;   // 0..4095
    int kk = tid >> 9;
    int rest = tid & 511;
    int t = rest >> 6;
    int lane = rest & 63;
    int q = lane >> 4;
    int ln = lane & 15;
    int n = t * 16 + ln;
    unsigned int hi[4], lo[4];
#pragma unroll
    for (int jj = 0; jj < 4; jj++) {
      unsigned short h0, h1, l0, l1;
      {
        float v = W1[(kk * 32 + q * 8 + jj * 2) * F1 + n];
        h0 = f2bf(v); l0 = f2bf(v - bf2f(h0));
      }
      {
        float v = W1[(kk * 32 + q * 8 + jj * 2 + 1) * F1 + n];
        h1 = f2bf(v); l1 = f2bf(v - bf2f(h1));
      }
      hi[jj] = (unsigned int)h0 | ((unsigned int)h1 << 16);
      lo[jj] = (unsigned int)l0 | ((unsigned int)l1 << 16);
    }
    size_t base = (size_t)tid * 8;
    *(uint4*)&wHi[base] = make_uint4(hi[0], hi[1], hi[2], hi[3]);
    *(uint4*)&wLo[base] = make_uint4(lo[0], lo[1], lo[2], lo[3]);
  } else {
    // ---- bin role: bucketed counting sort (line-local writes) ----
    int* ls = smem;
    int* ld = smem + EB;
    int* lcnt = smem + 2 * EB;
    int* lcur = lcnt + NB;
    int* gbaseS = lcur + NB;
    int tid = threadIdx.x;
    size_t base = (size_t)(blockIdx.x - PREW) * EB;
    for (int t = tid; t < NB; t += 256) { lcnt[t] = 0; lcur[t] = 0; }
    __syncthreads();
#pragma unroll
    for (int l = 0; l < EB / 256; l++) {
      int li = l * 256 + tid;
      size_t idx = base + li;
      int s = 0, d = -1;
      if (idx < N_EDGES) {
        s = ei[idx];
        d = ei[N_EDGES + idx];
        atomicAdd(&lcnt[d >> 7], 1);
      }
      ls[li] = s;
      ld[li] = d;
    }
    __syncthreads();
    for (int t = tid; t < NB; t += 256) gbaseS[t] = atomicAdd(&gcnt[t], lcnt[t]);
    __syncthreads();
#pragma unroll
    for (int l = 0; l < EB / 256; l++) {
      int li = l * 256 + tid;
      int d = ld[li];
      if (d >= 0) {
        int b = d >> 7;
        int r = gbaseS[b] + atomicAdd(&lcur[b], 1);
        if (r >= CAP) r = CAP - 1;   // overflow guard (statistically impossible)
        gbucket[(size_t)b * CAP + r] = make_int2(ls[li], d);
      }
    }
  }
}

// ---------------- mid_kernel: gemm1 (blocks 0..781) U csr (blocks 782..1172) ------------
__global__ __launch_bounds__(256) void mid_kernel(
    const float* __restrict__ x, const unsigned short* __restrict__ wHi,
    const unsigned short* __restrict__ wLo,
    const float* __restrict__ a_src, const float* __restrict__ a_dst,
    unsigned short* __restrict__ h1b, float* __restrict__ as1, float* __restrict__ ad1,
    const int2* __restrict__ gbucket, const int* __restrict__ gcnt,
    int* __restrict__ row_ptr, int* __restrict__ col) {
  __shared__ short8 smem[2048];   // 32 KB arena, 16B aligned
  if (blockIdx.x < G1B) {
    // ================= gemm1 role (R2 structure; R7's 8-wave variant was neutral) =====
    short8 (*Bsh)[1024] = (short8(*)[1024])smem;  // [buf][0..511]=hi, [512..1023]=lo
    int bid = blockIdx.x;
    int tid = threadIdx.x;
    int w = tid >> 6;
    int lane = tid & 63;
    int q = lane >> 4;
    int ln = lane & 15;
    int rowBase = bid * 64 + w * 16;
    int rowA = rowBase + ln;
    int rowAc = rowA < N_NODES ? rowA : N_NODES - 1;
    float4v acc[8];
#pragma unroll
    for (int t = 0; t < 8; t++) acc[t] = (float4v){0.f, 0.f, 0.f, 0.f};
    const short8* bhp = (const short8*)wHi;
    const short8* blp = (const short8*)wLo;

    auto prefetch = [&](int kk, int buf) {
#pragma unroll
      for (int c = 0; c < 2; c++) {
        int chunk = w * 2 + c;   // 0..7, 64 elements each
        gload_lds16(bhp + (size_t)kk * 512 + chunk * 64 + lane, &Bsh[buf][chunk * 64]);
        gload_lds16(blp + (size_t)kk * 512 + chunk * 64 + lane, &Bsh[buf][512 + chunk * 64]);
      }
    };

    const float4* xbase = (const float4*)(x + (size_t)rowAc * IN_DIM + q * 8);
    float4 a0 = xbase[0];
    float4 a1 = xbase[1];
    prefetch(0, 0);
    __syncthreads();   // drains vmcnt: slab 0 + a0/a1 resident

#pragma unroll 1
    for (int kk = 0; kk < 8; kk++) {
      int buf = kk & 1;
      if (kk < 7) prefetch(kk + 1, buf ^ 1);   // overlaps with compute below
      int kn = (kk < 7) ? kk + 1 : 7;
      float4 n0 = xbase[kn * 8];
      float4 n1 = xbase[kn * 8 + 1];
      float av[8] = {a0.x, a0.y, a0.z, a0.w, a1.x, a1.y, a1.z, a1.w};
      short8 ahi, alo;
#pragma unroll
      for (int j = 0; j < 8; j++) {
        unsigned short hh = f2bf(av[j]);
        ahi[j] = (short)hh;
        alo[j] = (short)f2bf(av[j] - bf2f(hh));
      }
      const short8* bs = &Bsh[buf][0];
#pragma unroll
      for (int t = 0; t < 8; t++) {
        short8 bh = bs[t * 64 + lane];
        short8 bl = bs[512 + t * 64 + lane];
        acc[t] = __builtin_amdgcn_mfma_f32_16x16x32_bf16(ahi, bh, acc[t], 0, 0, 0);
        acc[t] = __builtin_amdgcn_mfma_f32_16x16x32_bf16(ahi, bl, acc[t], 0, 0, 0);
        acc[t] = __builtin_amdgcn_mfma_f32_16x16x32_bf16(alo, bh, acc[t], 0, 0, 0);
      }
      a0 = n0;
      a1 = n1;
      if (kk < 7) __syncthreads();
    }

    float asv[8], adv[8];
#pragma unroll
    for (int t = 0; t < 8; t++) {
      asv[t] = a_src[t * 16 + ln];
      adv[t] = a_dst[t * 16 + ln];
    }
#pragma unroll
    for (int reg = 0; reg < 4; reg++) {
      int r = rowBase + q * 4 + reg;
      bool valid = (r < N_NODES);
      if (valid) {
#pragma unroll
        for (int t = 0; t < 8; t++)
          h1b[(size_t)r * F1 + t * 16 + ln] = f2bf(acc[t][reg]);
      }
#pragma unroll
      for (int h = 0; h < 4; h++) {
        float sa = acc[2 * h][reg] * asv[2 * h] + acc[2 * h + 1][reg] * asv[2 * h + 1];
        float sd = acc[2 * h][reg] * adv[2 * h] + acc[2 * h + 1][reg] * adv[2 * h + 1];
#pragma unroll
        for (int off = 1; off < 16; off <<= 1) {
          sa += __shfl_xor(sa, off);
          sd += __shfl_xor(sd, off);
        }
        if (ln == 0 && valid) {
          as1[r * 4 + h] = sa;
          ad1[r * 4 + h] = sd;
        }
      }
    }
  } else {
    // ================= csr role (bucketscan folded in as per-block reduce) =============
    int2* ent = (int2*)smem;                 // CAP * 8 = 24576 B
    int* hcnt = (int*)(ent + CAP);           // 512 B
    int* sc   = hcnt + 128;                  // 512 B
    int* cur  = sc + 128;                    // 512 B
    int* red  = cur + 128;                   // 16 B   (total 26128 B < 32768)
    int b = blockIdx.x - G1B;
    int tid = threadIdx.x;
    int cnt = gcnt[b]; if (cnt > CAP) cnt = CAP;
    if (tid < 128) hcnt[tid] = 0;
    // base = sum(gcnt[0..b-1]) : 2-round read + wave reduce + cross-wave via LDS
    int part = 0;
    for (int i = tid; i < b; i += 256) part += gcnt[i];
#pragma unroll
    for (int off = 32; off > 0; off >>= 1) part += __shfl_xor(part, off);
    if ((tid & 63) == 0) red[tid >> 6] = part;
    __syncthreads();
    int base = red[0] + red[1] + red[2] + red[3];
    for (int i = tid; i < cnt; i += 256) {
      int2 e = gbucket[(size_t)b * CAP + i];
      ent[i] = e;
      atomicAdd(&hcnt[e.y & 127], 1);
    }
    __syncthreads();
    if (tid < 128) sc[tid] = hcnt[tid];
    __syncthreads();
    for (int off = 1; off < 128; off <<= 1) {
      int t = 0;
      if (tid < 128 && tid >= off) t = sc[tid - off];
      __syncthreads();
      if (tid < 128) sc[tid] += t;
      __syncthreads();
    }
    if (tid < 128) {
      int excl = sc[tid] - hcnt[tid];
      cur[tid] = excl;
      int node = (b << 7) + tid;
      if (node < N_NODES) row_ptr[node] = base + excl;
    }
    if (b == 0 && tid == 0) row_ptr[N_NODES] = N_EDGES;
    __syncthreads();
    for (int i = tid; i < cnt; i += 256) {
      int2 e = ent[i];
      int r = atomicAdd(&cur[e.y & 127], 1);
      col[base + r] = e.x;
    }
  }
}

// ---------------- layer-1: single-pass gather, 4-way ILP (R8) ----------------
// R3 counters (VALUBusy 50%, hbm 35%, occ 70%) -> dependent-chain latency bound.
// R8: 4 independent edge chains in flight per slot (was 2) -> one exposed
// round-trip amortized over 4 edges. Same index set / guards as R4.
__global__ __launch_bounds__(256) void gather1_kernel(
    const unsigned short* __restrict__ h1b, const float* __restrict__ as1,
    const float* __restrict__ ad1, const float* __restrict__ b1,
    const int* __restrict__ row_ptr, const int* __restrict__ col,
    float* __restrict__ x2) {
  int wv = threadIdx.x >> 6;
  int n = blockIdx.x * 4 + wv;
  if (n >= N_NODES) return;
  int lane = threadIdx.x & 63;
  int start = row_ptr[n];
  int deg = row_ptr[n + 1] - start;
  int slot = lane >> 4;
  int lane16 = lane & 15;
  int head = lane16 >> 2;
  float adh = ad1[n * 4 + head];
  float4 accA = make_float4(0.f, 0.f, 0.f, 0.f);
  float4 accB = make_float4(0.f, 0.f, 0.f, 0.f);
  float dn = 0.f;
  int i = slot;
  // 4-way: edges i, i+4, i+8, i+12 (i+12<=deg guarantees first three < deg)
  for (; i + 12 <= deg; i += 16) {
    int sA = col[start + i];
    int sB = col[start + i + 4];
    int sC = col[start + i + 8];
    int sD = (i + 12 < deg) ? col[start + i + 12] : n;
    float eA = __expf(lrelu(as1[sA * 4 + head] + adh));
    float eB = __expf(lrelu(as1[sB * 4 + head] + adh));
    float eC = __expf(lrelu(as1[sC * 4 + head] + adh));
    float eD = __expf(lrelu(as1[sD * 4 + head] + adh));
    uint4 uA = *(const uint4*)(h1b + (size_t)sA * F1 + lane16 * 8);
    uint4 uB = *(const uint4*)(h1b + (size_t)sB * F1 + lane16 * 8);
    uint4 uC = *(const uint4*)(h1b + (size_t)sC * F1 + lane16 * 8);
    uint4 uD = *(const uint4*)(h1b + (size_t)sD * F1 + lane16 * 8);
    dn += (eA + eB) + (eC + eD);
    accA.x += eA * bflo(uA.x); accA.y += eA * bfhi(uA.x);
    accA.z += eA * bflo(uA.y); accA.w += eA * bfhi(uA.y);
    accB.x += eA * bflo(uA.z); accB.y += eA * bfhi(uA.z);
    accB.z += eA * bflo(uA.w); accB.w += eA * bfhi(uA.w);
    accA.x += eB * bflo(uB.x); accA.y += eB * bfhi(uB.x);
    accA.z += eB * bflo(uB.y); accA.w += eB * bfhi(uB.y);
    accB.x += eB * bflo(uB.z); accB.y += eB * bfhi(uB.z);
    accB.z += eB * bflo(uB.w); accB.w += eB * bfhi(uB.w);
    accA.x += eC * bflo(uC.x); accA.y += eC * bfhi(uC.x);
    accA.z += eC * bflo(uC.y); accA.w += eC * bfhi(uC.y);
    accB.x += eC * bflo(uC.z); accB.y += eC * bfhi(uC.z);
    accB.z += eC * bflo(uC.w); accB.w += eC * bfhi(uC.w);
    accA.x += eD * bflo(uD.x); accA.y += eD * bfhi(uD.x);
    accA.z += eD * bflo(uD.y); accA.w += eD * bfhi(uD.y);
    accB.x += eD * bflo(uD.z); accB.y += eD * bfhi(uD.z);
    accB.z += eD * bflo(uD.w); accB.w += eD * bfhi(uD.w);
  }
  // 2-way remainder
  for (; i + 4 <= deg; i += 8) {
    int sA = col[start + i];
    int sB = (i + 4 < deg) ? col[start + i + 4] : n;
    float eA = __expf(lrelu(as1[sA * 4 + head] + adh));
    float eB = __expf(lrelu(as1[sB * 4 + head] + adh));
    uint4 uA = *(const uint4*)(h1b + (size_t)sA * F1 + lane16 * 8);
    uint4 uB = *(const uint4*)(h1b + (size_t)sB * F1 + lane16 * 8);
    dn += eA + eB;
    accA.x += eA * bflo(uA.x); accA.y += eA * bfhi(uA.x);
    accA.z += eA * bflo(uA.y); accA.w += eA * bfhi(uA.y);
    accB.x += eA * bflo(uA.z); accB.y += eA * bfhi(uA.z);
    accB.z += eA * bflo(uA.w); accB.w += eA * bfhi(uA.w);
    accA.x += eB * bflo(uB.x); accA.y += eB * bfhi(uB.x);
    accA.z += eB * bflo(uB.y); accA.w += eB * bfhi(uB.y);
    accB.x += eB * bflo(uB.z); accB.y += eB * bfhi(uB.z);
    accB.z += eB * bflo(uB.w); accB.w += eB * bfhi(uB.w);
  }
  if (i <= deg) {   // at most one remaining edge per slot
    int s = (i < deg) ? col[start + i] : n;
    float e = __expf(lrelu(as1[s * 4 + head] + adh));
    uint4 u = *(const uint4*)(h1b + (size_t)s * F1 + lane16 * 8);
    dn += e;
    accA.x += e * bflo(u.x); accA.y += e * bfhi(u.x);
    accA.z += e * bflo(u.y); accA.w += e * bfhi(u.y);
    accB.x += e * bflo(u.z); accB.y += e * bfhi(u.z);
    accB.z += e * bflo(u.w); accB.w += e * bfhi(u.w);
  }
  // cross-slot reduce: slot bits are lane bits 4,5 (xor butterfly); dn is 9th value
#pragma unroll
  for (int off = 16; off <= 32; off <<= 1) {
    accA.x += __shfl_xor(accA.x, off); accA.y += __shfl_xor(accA.y, off);
    accA.z += __shfl_xor(accA.z, off); accA.w += __shfl_xor(accA.w, off);
    accB.x += __shfl_xor(accB.x, off); accB.y += __shfl_xor(accB.y, off);
    accB.z += __shfl_xor(accB.z, off); accB.w += __shfl_xor(accB.w, off);
    dn += __shfl_xor(dn, off);
  }
  if (slot == 0) {
    float rsh = 1.f / (dn + 1e-16f);
    float4 bA = *(const float4*)&b1[lane16 * 8];
    float4 bB = *(const float4*)&b1[lane16 * 8 + 4];
    float4 oA, oB;
    oA.x = fmaxf(accA.x * rsh + bA.x, 0.f); oA.y = fmaxf(accA.y * rsh + bA.y, 0.f);
    oA.z = fmaxf(accA.z * rsh + bA.z, 0.f); oA.w = fmaxf(accA.w * rsh + bA.w, 0.f);
    oB.x = fmaxf(accB.x * rsh + bB.x, 0.f); oB.y = fmaxf(accB.y * rsh + bB.y, 0.f);
    oB.z = fmaxf(accB.z * rsh + bB.z, 0.f); oB.w = fmaxf(accB.w * rsh + bB.w, 0.f);
    *(float4*)&x2[(size_t)n * F1 + lane16 * 8] = oA;
    *(float4*)&x2[(size_t)n * F1 + lane16 * 8 + 4] = oB;
  }
}

// ---------------- GEMM2 tiled + alpha2 fused: h2b = x2@W2 (bf16), as2/ad2 ----------------
__global__ __launch_bounds__(256) void gemm2_kernel(
    const float* __restrict__ x2, const float* __restrict__ W2,
    const float* __restrict__ asv, const float* __restrict__ adv,
    unsigned short* __restrict__ h2b, float* __restrict__ as2, float* __restrict__ ad2) {
  __shared__ float xs[64][132];
  __shared__ float W2s[128][44];
  __shared__ float asv_s[40], adv_s[40];
  int tid = threadIdx.x;
  int bm = blockIdx.x * 64;
#pragma unroll
  for (int l = 0; l < 8; l++) {
    int idx = tid + l * 256;
    int r = idx >> 5;
    int c4 = (idx & 31) << 2;
    float4 v = make_float4(0.f, 0.f, 0.f, 0.f);
    if (bm + r < N_NODES) v = *(const float4*)&x2[(size_t)(bm + r) * F1 + c4];
    *(float4*)&xs[r][c4] = v;
  }
#pragma unroll
  for (int l = 0; l < 5; l++) {
    int idx = tid + l * 256;
    int k = idx / 10;
    int c4 = (idx - k * 10) * 4;
    *(float4*)&W2s[k][c4] = *(const float4*)&W2[k * OUT_DIM + c4];
  }
  if (tid < OUT_DIM) { asv_s[tid] = asv[tid]; adv_s[tid] = adv[tid]; }
  __syncthreads();
  int r = tid >> 2;
  int cb = (tid & 3) * 10;
  float acc[10] = {0.f};
  for (int k = 0; k < F1; k++) {
    float xv = xs[r][k];
#pragma unroll
    for (int c = 0; c < 10; c++) acc[c] += xv * W2s[k][cb + c];
  }
  int grow = bm + r;
  float sa = 0.f, sd = 0.f;
#pragma unroll
  for (int c = 0; c < 10; c++) {
    sa += acc[c] * asv_s[cb + c];
    sd += acc[c] * adv_s[cb + c];
  }
#pragma unroll
  for (int off = 1; off < 4; off <<= 1) {
    sa += __shfl_xor(sa, off);
    sd += __shfl_xor(sd, off);
  }
  if (grow < N_NODES) {
#pragma unroll
    for (int c = 0; c < 10; c += 2) {
      unsigned int p = ((unsigned int)f2bf(acc[c + 1]) << 16) | f2bf(acc[c]);
      *(unsigned int*)&h2b[(size_t)grow * OUT_DIM + cb + c] = p;
    }
    if ((tid & 3) == 0) { as2[grow] = sa; ad2[grow] = sd; }
  }
}

// ---------------- layer-2: single-pass gather + log_softmax, 2-way ILP (R8) ----------------
__global__ __launch_bounds__(256) void gather2_kernel(
    const unsigned short* __restrict__ h2b, const float* __restrict__ as2,
    const float* __restrict__ ad2, const float* __restrict__ b2,
    const int* __restrict__ row_ptr, const int* __restrict__ col,
    float* __restrict__ out) {
  int wv = threadIdx.x >> 6;
  int n = blockIdx.x * 4 + wv;
  if (n >= N_NODES) return;
  int lane = threadIdx.x & 63;
  int start = row_ptr[n];
  int deg = row_ptr[n + 1] - start;
  float adh = ad2[n];
  // 12 slots x 5 lanes (16B bf16x8, row=80B); lanes 60..63 idle
  int slot = lane / 5;
  int c = lane - slot * 5;
  float4 accA = make_float4(0.f, 0.f, 0.f, 0.f);
  float4 accB = make_float4(0.f, 0.f, 0.f, 0.f);
  float dn = 0.f;
  if (slot < 12) {
    int i = slot;
    // 2-way: edges i and i+12 (i+12<=deg guarantees i < deg)
    for (; i + 12 <= deg; i += 24) {
      int sA = col[start + i];
      int sB = (i + 12 < deg) ? col[start + i + 12] : n;
      float eA = __expf(lrelu(as2[sA] + adh));
      float eB = __expf(lrelu(as2[sB] + adh));
      uint4 uA = *(const uint4*)(h2b + (size_t)sA * OUT_DIM + c * 8);
      uint4 uB = *(const uint4*)(h2b + (size_t)sB * OUT_DIM + c * 8);
      dn += eA + eB;
      accA.x += eA * bflo(uA.x); accA.y += eA * bfhi(uA.x);
      accA.z += eA * bflo(uA.y); accA.w += eA * bfhi(uA.y);
      accB.x += eA * bflo(uA.z); accB.y += eA * bfhi(uA.z);
      accB.z += eA * bflo(uA.w); accB.w += eA * bfhi(uA.w);
      accA.x += eB * bflo(uB.x); accA.y += eB * bfhi(uB.x);
      accA.z += eB * bflo(uB.y); accA.w += eB * bfhi(uB.y);
      accB.x += eB * bflo(uB.z); accB.y += eB * bfhi(uB.z);
      accB.z += eB * bflo(uB.w); accB.w += eB * bfhi(uB.w);
    }
    if (i <= deg) {
      int src = (i < deg) ? col[start + i] : n;
      float e = __expf(lrelu(as2[src] + adh));
      uint4 u = *(const uint4*)(h2b + (size_t)src * OUT_DIM + c * 8);
      dn += e;
      accA.x += e * bflo(u.x); accA.y += e * bfhi(u.x);
      accA.z += e * bflo(u.y); accA.w += e * bfhi(u.y);
      accB.x += e * bflo(u.z); accB.y += e * bfhi(u.z);
      accB.z += e * bflo(u.w); accB.w += e * bfhi(u.w);
    }
  }
  // cross-slot reduce (12 slots); temps read before update; dn is v[8]
  float v[9] = {accA.x, accA.y, accA.z, accA.w, accB.x, accB.y, accB.z, accB.w, dn};
#pragma unroll
  for (int k = 0; k < 9; k++) v[k] += __shfl(v[k], lane + 30);
#pragma unroll
  for (int k = 0; k < 9; k++) v[k] += __shfl(v[k], lane + 15);
  {
    float t1[9], t2[9];
#pragma unroll
    for (int k = 0; k < 9; k++) t1[k] = __shfl(v[k], lane + 5);
#pragma unroll
    for (int k = 0; k < 9; k++) t2[k] = __shfl(v[k], lane + 10);
#pragma unroll
    for (int k = 0; k < 9; k++) v[k] += t1[k] + t2[k];
  }
  bool owner = (slot == 0);
  float vals[8];
  float lmax = -1e30f, lsum = 0.f;
  if (owner) {
    float rs = 1.f / (v[8] + 1e-16f);
#pragma unroll
    for (int k = 0; k < 8; k++) {
      vals[k] = v[k] * rs + b2[c * 8 + k];
      lmax = fmaxf(lmax, vals[k]);
    }
  }
  float gmax = lmax;
#pragma unroll
  for (int off = 32; off > 0; off >>= 1) gmax = fmaxf(gmax, __shfl_xor(gmax, off));
  if (owner) {
#pragma unroll
    for (int k = 0; k < 8; k++) lsum += __expf(vals[k] - gmax);
  }
#pragma unroll
  for (int off = 32; off > 0; off >>= 1) lsum += __shfl_xor(lsum, off);
  if (owner) {
    float lse = gmax + __logf(lsum);
    float4 oA = make_float4(vals[0] - lse, vals[1] - lse, vals[2] - lse, vals[3] - lse);
    float4 oB = make_float4(vals[4] - lse, vals[5] - lse, vals[6] - lse, vals[7] - lse);
    *(float4*)&out[(size_t)n * OUT_DIM + c * 8] = oA;
    *(float4*)&out[(size_t)n * OUT_DIM + c * 8 + 4] = oB;
  }
}

extern "C" void kernel_launch(void* const* d_in, const int* in_sizes, int n_in,
                              void* d_out, int out_size, void* d_ws, size_t ws_size,
                              hipStream_t stream) {
  const float* x      = (const float*)d_in[0];
  const int*   ei     = (const int*)d_in[1];
  const float* W1     = (const float*)d_in[2];
  const float* a_src1 = (const float*)d_in[3];
  const float* a_dst1 = (const float*)d_in[4];
  const float* b1     = (const float*)d_in[5];
  const float* W2     = (const float*)d_in[6];
  const float* a_src2 = (const float*)d_in[7];
  const float* a_dst2 = (const float*)d_in[8];
  const float* b2     = (const float*)d_in[9];
  float* out = (float*)d_out;

  char* ws = (char*)d_ws;
  size_t off = 0;
  auto alloc = [&](size_t bytes) -> void* {
    void* p = ws + off;
    off += (bytes + 255) & ~(size_t)255;
    return p;
  };
  unsigned short* h1b = (unsigned short*)alloc((size_t)N_NODES * F1 * 2);       // 12.8 MB
  unsigned short* h2b = (unsigned short*)alloc((size_t)N_NODES * OUT_DIM * 2);  // 4 MB
  unsigned short* wHi = (unsigned short*)alloc((size_t)IN_DIM * F1 * 2);        // 64 KB
  unsigned short* wLo = (unsigned short*)alloc((size_t)IN_DIM * F1 * 2);        // 64 KB
  float* as1    = (float*)alloc((size_t)N_NODES * HEADS * 4);
  float* ad1    = (float*)alloc((size_t)N_NODES * HEADS * 4);
  float* x2     = (float*)alloc((size_t)N_NODES * F1 * 4);
  float* as2    = (float*)alloc((size_t)N_NODES * 4);
  float* ad2    = (float*)alloc((size_t)N_NODES * 4);
  int* row_ptr  = (int*)alloc((size_t)(N_NODES + 1) * 4);
  int* col      = (int*)alloc((size_t)N_EDGES * 4);
  int* gcnt     = (int*)alloc((size_t)NB * 4);
  int2* gbucket = (int2*)alloc((size_t)NB * CAP * 8);                           // 9.6 MB

  hipMemsetAsync(gcnt, 0, (size_t)NB * 4, stream);
  // pre: w1pack (16 blocks) U bin (196 blocks)
  pre_kernel<<<PREW + (N_EDGES + EB - 1) / EB, 256, 0, stream>>>(W1, wHi, wLo, ei, gcnt, gbucket);
  // mid: gemm1 (782 blocks) U csr-with-inline-scan (391 blocks)
  mid_kernel<<<G1B + NB, 256, 0, stream>>>(x, wHi, wLo, a_src1, a_dst1, h1b, as1, ad1,
                                           gbucket, gcnt, row_ptr, col);
  gather1_kernel<<<(N_NODES + 3) / 4, 256, 0, stream>>>(h1b, as1, ad1, b1, row_ptr, col, x2);

  gemm2_kernel<<<(N_NODES + 63) / 64, 256, 0, stream>>>(x2, W2, a_src2, a_dst2, h2b, as2, ad2);
  gather2_kernel<<<(N_NODES + 3) / 4, 256, 0, stream>>>(h2b, as2, ad2, b2, row_ptr, col, out);
}

// Round 9
// 215.604 us; speedup vs baseline: 1.0981x; 1.0825x over previous
//
#include <hip/hip_runtime.h>
#include <math.h>

#define N_NODES 50000
#define N_EDGES 800000
#define IN_DIM  256
#define F1      128   // HEADS*HID
#define HEADS   4
#define OUT_DIM 40
#define N2PAD   48    // OUT_DIM padded to 3 MFMA tiles
#define NEG     0.2f

// CSR bucket sort params
#define NB   391     // buckets of 128 nodes: 50000/128 -> 391
#define CAP  3072    // per-bucket capacity (mean 2048, sigma ~45 -> >20 sigma margin)
#define EB   4096    // edges per bin block
#define PREW 16      // w1pack blocks inside pre_kernel
#define W2PB 3       // w2pack blocks inside pre_kernel (768 threads)
#define G1B  782     // gemm1 blocks inside mid_kernel: (N_NODES+63)/64

typedef __attribute__((ext_vector_type(8))) short short8;    // 8 bf16 in 4 VGPRs
typedef __attribute__((ext_vector_type(4))) float float4v;   // MFMA C/D

// ---- bf16 helpers (RNE pack, shift unpack) ----
__device__ __forceinline__ unsigned short f2bf(float f) {
  unsigned int u = __float_as_uint(f);
  u += 0x7FFF + ((u >> 16) & 1);
  return (unsigned short)(u >> 16);
}
__device__ __forceinline__ float bf2f(unsigned short h) {
  return __uint_as_float((unsigned int)h << 16);
}
__device__ __forceinline__ float bflo(unsigned int u) { return __uint_as_float(u << 16); }
__device__ __forceinline__ float bfhi(unsigned int u) { return __uint_as_float(u & 0xffff0000u); }

__device__ __forceinline__ float lrelu(float e) { return e > 0.f ? e : e * NEG; }

// async global->LDS DMA, 16B per lane. LDS dest must be wave-uniform base
// (HW adds lane*16); global src is per-lane.
__device__ __forceinline__ void gload_lds16(const void* g, void* l) {
  __builtin_amdgcn_global_load_lds(
      (const __attribute__((address_space(1))) unsigned int*)g,
      (__attribute__((address_space(3))) unsigned int*)l, 16, 0, 0);
}

// ---------------- pre_kernel: w1pack (0..15) U w2pack (16..18) U bin (19..214) ----------
__global__ __launch_bounds__(256) void pre_kernel(const float* __restrict__ W1,
                                                  unsigned short* __restrict__ wHi,
                                                  unsigned short* __restrict__ wLo,
                                                  const float* __restrict__ W2,
                                                  unsigned short* __restrict__ w2h,
                                                  unsigned short* __restrict__ w2l,
                                                  const int* __restrict__ ei,
                                                  int* __restrict__ gcnt,
                                                  int2* __restrict__ gbucket) {
  __shared__ int smem[EB * 2 + NB * 3];   // 37.5 KB arena (bin role)
  if (blockIdx.x < PREW) {
    // ---- w1pack role: W1 -> MFMA B-fragment packing (hi/lo split) ----
    int tid = blockIdx.x * 256 + threadIdx.x;   // 0..4095
    int kk = tid >> 9;
    int rest = tid & 511;
    int t = rest >> 6;
    int lane = rest & 63;
    int q = lane >> 4;
    int ln = lane & 15;
    int n = t * 16 + ln;
    unsigned int hi[4], lo[4];
#pragma unroll
    for (int jj = 0; jj < 4; jj++) {
      unsigned short h0, h1, l0, l1;
      {
        float v = W1[(kk * 32 + q * 8 + jj * 2) * F1 + n];
        h0 = f2bf(v); l0 = f2bf(v - bf2f(h0));
      }
      {
        float v = W1[(kk * 32 + q * 8 + jj * 2 + 1) * F1 + n];
        h1 = f2bf(v); l1 = f2bf(v - bf2f(h1));
      }
      hi[jj] = (unsigned int)h0 | ((unsigned int)h1 << 16);
      lo[jj] = (unsigned int)l0 | ((unsigned int)l1 << 16);
    }
    size_t base = (size_t)tid * 8;
    *(uint4*)&wHi[base] = make_uint4(hi[0], hi[1], hi[2], hi[3]);
    *(uint4*)&wLo[base] = make_uint4(lo[0], lo[1], lo[2], lo[3]);
  } else if (blockIdx.x < PREW + W2PB) {
    // ---- w2pack role: W2 [128][40] -> MFMA B-frags, N padded to 48 (R9) ----
    int fid = (blockIdx.x - PREW) * 256 + threadIdx.x;   // 0..767
    if (fid < 768) {
      int kk = fid / 192;          // 0..3 (K groups of 32)
      int rest = fid - kk * 192;
      int t = rest >> 6;           // 0..2 (N tiles of 16)
      int lane = rest & 63;
      int q = lane >> 4;
      int ln = lane & 15;
      int n = t * 16 + ln;
      unsigned int hi[4], lo[4];
#pragma unroll
      for (int jj = 0; jj < 4; jj++) {
        unsigned short h0, h1, l0, l1;
        {
          float v = (n < OUT_DIM) ? W2[(kk * 32 + q * 8 + jj * 2) * OUT_DIM + n] : 0.f;
          h0 = f2bf(v); l0 = f2bf(v - bf2f(h0));
        }
        {
          float v = (n < OUT_DIM) ? W2[(kk * 32 + q * 8 + jj * 2 + 1) * OUT_DIM + n] : 0.f;
          h1 = f2bf(v); l1 = f2bf(v - bf2f(h1));
        }
        hi[jj] = (unsigned int)h0 | ((unsigned int)h1 << 16);
        lo[jj] = (unsigned int)l0 | ((unsigned int)l1 << 16);
      }
      size_t base = (size_t)fid * 8;
      *(uint4*)&w2h[base] = make_uint4(hi[0], hi[1], hi[2], hi[3]);
      *(uint4*)&w2l[base] = make_uint4(lo[0], lo[1], lo[2], lo[3]);
    }
  } else {
    // ---- bin role: bucketed counting sort (line-local writes) ----
    int* ls = smem;
    int* ld = smem + EB;
    int* lcnt = smem + 2 * EB;
    int* lcur = lcnt + NB;
    int* gbaseS = lcur + NB;
    int tid = threadIdx.x;
    size_t base = (size_t)(blockIdx.x - PREW - W2PB) * EB;
    for (int t = tid; t < NB; t += 256) { lcnt[t] = 0; lcur[t] = 0; }
    __syncthreads();
#pragma unroll
    for (int l = 0; l < EB / 256; l++) {
      int li = l * 256 + tid;
      size_t idx = base + li;
      int s = 0, d = -1;
      if (idx < N_EDGES) {
        s = ei[idx];
        d = ei[N_EDGES + idx];
        atomicAdd(&lcnt[d >> 7], 1);
      }
      ls[li] = s;
      ld[li] = d;
    }
    __syncthreads();
    for (int t = tid; t < NB; t += 256) gbaseS[t] = atomicAdd(&gcnt[t], lcnt[t]);
    __syncthreads();
#pragma unroll
    for (int l = 0; l < EB / 256; l++) {
      int li = l * 256 + tid;
      int d = ld[li];
      if (d >= 0) {
        int b = d >> 7;
        int r = gbaseS[b] + atomicAdd(&lcur[b], 1);
        if (r >= CAP) r = CAP - 1;   // overflow guard (statistically impossible)
        gbucket[(size_t)b * CAP + r] = make_int2(ls[li], d);
      }
    }
  }
}

// ---------------- mid_kernel: gemm1 (blocks 0..781) U csr (blocks 782..1172) ------------
__global__ __launch_bounds__(256) void mid_kernel(
    const float* __restrict__ x, const unsigned short* __restrict__ wHi,
    const unsigned short* __restrict__ wLo,
    const float* __restrict__ a_src, const float* __restrict__ a_dst,
    unsigned short* __restrict__ h1b, float* __restrict__ as1, float* __restrict__ ad1,
    const int2* __restrict__ gbucket, const int* __restrict__ gcnt,
    int* __restrict__ row_ptr, int* __restrict__ col) {
  __shared__ short8 smem[2048];   // 32 KB arena, 16B aligned
  if (blockIdx.x < G1B) {
    // ================= gemm1 role (R2 structure) =================
    short8 (*Bsh)[1024] = (short8(*)[1024])smem;  // [buf][0..511]=hi, [512..1023]=lo
    int bid = blockIdx.x;
    int tid = threadIdx.x;
    int w = tid >> 6;
    int lane = tid & 63;
    int q = lane >> 4;
    int ln = lane & 15;
    int rowBase = bid * 64 + w * 16;
    int rowA = rowBase + ln;
    int rowAc = rowA < N_NODES ? rowA : N_NODES - 1;
    float4v acc[8];
#pragma unroll
    for (int t = 0; t < 8; t++) acc[t] = (float4v){0.f, 0.f, 0.f, 0.f};
    const short8* bhp = (const short8*)wHi;
    const short8* blp = (const short8*)wLo;

    auto prefetch = [&](int kk, int buf) {
#pragma unroll
      for (int c = 0; c < 2; c++) {
        int chunk = w * 2 + c;   // 0..7, 64 elements each
        gload_lds16(bhp + (size_t)kk * 512 + chunk * 64 + lane, &Bsh[buf][chunk * 64]);
        gload_lds16(blp + (size_t)kk * 512 + chunk * 64 + lane, &Bsh[buf][512 + chunk * 64]);
      }
    };

    const float4* xbase = (const float4*)(x + (size_t)rowAc * IN_DIM + q * 8);
    float4 a0 = xbase[0];
    float4 a1 = xbase[1];
    prefetch(0, 0);
    __syncthreads();   // drains vmcnt: slab 0 + a0/a1 resident

#pragma unroll 1
    for (int kk = 0; kk < 8; kk++) {
      int buf = kk & 1;
      if (kk < 7) prefetch(kk + 1, buf ^ 1);   // overlaps with compute below
      int kn = (kk < 7) ? kk + 1 : 7;
      float4 n0 = xbase[kn * 8];
      float4 n1 = xbase[kn * 8 + 1];
      float av[8] = {a0.x, a0.y, a0.z, a0.w, a1.x, a1.y, a1.z, a1.w};
      short8 ahi, alo;
#pragma unroll
      for (int j = 0; j < 8; j++) {
        unsigned short hh = f2bf(av[j]);
        ahi[j] = (short)hh;
        alo[j] = (short)f2bf(av[j] - bf2f(hh));
      }
      const short8* bs = &Bsh[buf][0];
#pragma unroll
      for (int t = 0; t < 8; t++) {
        short8 bh = bs[t * 64 + lane];
        short8 bl = bs[512 + t * 64 + lane];
        acc[t] = __builtin_amdgcn_mfma_f32_16x16x32_bf16(ahi, bh, acc[t], 0, 0, 0);
        acc[t] = __builtin_amdgcn_mfma_f32_16x16x32_bf16(ahi, bl, acc[t], 0, 0, 0);
        acc[t] = __builtin_amdgcn_mfma_f32_16x16x32_bf16(alo, bh, acc[t], 0, 0, 0);
      }
      a0 = n0;
      a1 = n1;
      if (kk < 7) __syncthreads();
    }

    float asv[8], adv[8];
#pragma unroll
    for (int t = 0; t < 8; t++) {
      asv[t] = a_src[t * 16 + ln];
      adv[t] = a_dst[t * 16 + ln];
    }
#pragma unroll
    for (int reg = 0; reg < 4; reg++) {
      int r = rowBase + q * 4 + reg;
      bool valid = (r < N_NODES);
      if (valid) {
#pragma unroll
        for (int t = 0; t < 8; t++)
          h1b[(size_t)r * F1 + t * 16 + ln] = f2bf(acc[t][reg]);
      }
#pragma unroll
      for (int h = 0; h < 4; h++) {
        float sa = acc[2 * h][reg] * asv[2 * h] + acc[2 * h + 1][reg] * asv[2 * h + 1];
        float sd = acc[2 * h][reg] * adv[2 * h] + acc[2 * h + 1][reg] * adv[2 * h + 1];
#pragma unroll
        for (int off = 1; off < 16; off <<= 1) {
          sa += __shfl_xor(sa, off);
          sd += __shfl_xor(sd, off);
        }
        if (ln == 0 && valid) {
          as1[r * 4 + h] = sa;
          ad1[r * 4 + h] = sd;
        }
      }
    }
  } else {
    // ================= csr role (bucketscan folded in as per-block reduce) =============
    int2* ent = (int2*)smem;                 // CAP * 8 = 24576 B
    int* hcnt = (int*)(ent + CAP);           // 512 B
    int* sc   = hcnt + 128;                  // 512 B
    int* cur  = sc + 128;                    // 512 B
    int* red  = cur + 128;                   // 16 B   (total 26128 B < 32768)
    int b = blockIdx.x - G1B;
    int tid = threadIdx.x;
    int cnt = gcnt[b]; if (cnt > CAP) cnt = CAP;
    if (tid < 128) hcnt[tid] = 0;
    // base = sum(gcnt[0..b-1]) : 2-round read + wave reduce + cross-wave via LDS
    int part = 0;
    for (int i = tid; i < b; i += 256) part += gcnt[i];
#pragma unroll
    for (int off = 32; off > 0; off >>= 1) part += __shfl_xor(part, off);
    if ((tid & 63) == 0) red[tid >> 6] = part;
    __syncthreads();
    int base = red[0] + red[1] + red[2] + red[3];
    for (int i = tid; i < cnt; i += 256) {
      int2 e = gbucket[(size_t)b * CAP + i];
      ent[i] = e;
      atomicAdd(&hcnt[e.y & 127], 1);
    }
    __syncthreads();
    if (tid < 128) sc[tid] = hcnt[tid];
    __syncthreads();
    for (int off = 1; off < 128; off <<= 1) {
      int t = 0;
      if (tid < 128 && tid >= off) t = sc[tid - off];
      __syncthreads();
      if (tid < 128) sc[tid] += t;
      __syncthreads();
    }
    if (tid < 128) {
      int excl = sc[tid] - hcnt[tid];
      cur[tid] = excl;
      int node = (b << 7) + tid;
      if (node < N_NODES) row_ptr[node] = base + excl;
    }
    if (b == 0 && tid == 0) row_ptr[N_NODES] = N_EDGES;
    __syncthreads();
    for (int i = tid; i < cnt; i += 256) {
      int2 e = ent[i];
      int r = atomicAdd(&cur[e.y & 127], 1);
      col[base + r] = e.x;
    }
  }
}

// ---------------- layer-1: single-pass gather, 4-way ILP (R8) ----------------
// R9: epilogue writes x2 as bf16 hi/lo pairs (split-precision format gemm2's MFMA
// consumes directly). Same bytes/lane, same coalescing as the old fp32 write.
__global__ __launch_bounds__(256) void gather1_kernel(
    const unsigned short* __restrict__ h1b, const float* __restrict__ as1,
    const float* __restrict__ ad1, const float* __restrict__ b1,
    const int* __restrict__ row_ptr, const int* __restrict__ col,
    unsigned short* __restrict__ x2h, unsigned short* __restrict__ x2l) {
  int wv = threadIdx.x >> 6;
  int n = blockIdx.x * 4 + wv;
  if (n >= N_NODES) return;
  int lane = threadIdx.x & 63;
  int start = row_ptr[n];
  int deg = row_ptr[n + 1] - start;
  int slot = lane >> 4;
  int lane16 = lane & 15;
  int head = lane16 >> 2;
  float adh = ad1[n * 4 + head];
  float4 accA = make_float4(0.f, 0.f, 0.f, 0.f);
  float4 accB = make_float4(0.f, 0.f, 0.f, 0.f);
  float dn = 0.f;
  int i = slot;
  // 4-way: edges i, i+4, i+8, i+12
  for (; i + 12 <= deg; i += 16) {
    int sA = col[start + i];
    int sB = col[start + i + 4];
    int sC = col[start + i + 8];
    int sD = (i + 12 < deg) ? col[start + i + 12] : n;
    float eA = __expf(lrelu(as1[sA * 4 + head] + adh));
    float eB = __expf(lrelu(as1[sB * 4 + head] + adh));
    float eC = __expf(lrelu(as1[sC * 4 + head] + adh));
    float eD = __expf(lrelu(as1[sD * 4 + head] + adh));
    uint4 uA = *(const uint4*)(h1b + (size_t)sA * F1 + lane16 * 8);
    uint4 uB = *(const uint4*)(h1b + (size_t)sB * F1 + lane16 * 8);
    uint4 uC = *(const uint4*)(h1b + (size_t)sC * F1 + lane16 * 8);
    uint4 uD = *(const uint4*)(h1b + (size_t)sD * F1 + lane16 * 8);
    dn += (eA + eB) + (eC + eD);
    accA.x += eA * bflo(uA.x); accA.y += eA * bfhi(uA.x);
    accA.z += eA * bflo(uA.y); accA.w += eA * bfhi(uA.y);
    accB.x += eA * bflo(uA.z); accB.y += eA * bfhi(uA.z);
    accB.z += eA * bflo(uA.w); accB.w += eA * bfhi(uA.w);
    accA.x += eB * bflo(uB.x); accA.y += eB * bfhi(uB.x);
    accA.z += eB * bflo(uB.y); accA.w += eB * bfhi(uB.y);
    accB.x += eB * bflo(uB.z); accB.y += eB * bfhi(uB.z);
    accB.z += eB * bflo(uB.w); accB.w += eB * bfhi(uB.w);
    accA.x += eC * bflo(uC.x); accA.y += eC * bfhi(uC.x);
    accA.z += eC * bflo(uC.y); accA.w += eC * bfhi(uC.y);
    accB.x += eC * bflo(uC.z); accB.y += eC * bfhi(uC.z);
    accB.z += eC * bflo(uC.w); accB.w += eC * bfhi(uC.w);
    accA.x += eD * bflo(uD.x); accA.y += eD * bfhi(uD.x);
    accA.z += eD * bflo(uD.y); accA.w += eD * bfhi(uD.y);
    accB.x += eD * bflo(uD.z); accB.y += eD * bfhi(uD.z);
    accB.z += eD * bflo(uD.w); accB.w += eD * bfhi(uD.w);
  }
  // 2-way remainder
  for (; i + 4 <= deg; i += 8) {
    int sA = col[start + i];
    int sB = (i + 4 < deg) ? col[start + i + 4] : n;
    float eA = __expf(lrelu(as1[sA * 4 + head] + adh));
    float eB = __expf(lrelu(as1[sB * 4 + head] + adh));
    uint4 uA = *(const uint4*)(h1b + (size_t)sA * F1 + lane16 * 8);
    uint4 uB = *(const uint4*)(h1b + (size_t)sB * F1 + lane16 * 8);
    dn += eA + eB;
    accA.x += eA * bflo(uA.x); accA.y += eA * bfhi(uA.x);
    accA.z += eA * bflo(uA.y); accA.w += eA * bfhi(uA.y);
    accB.x += eA * bflo(uA.z); accB.y += eA * bfhi(uA.z);
    accB.z += eA * bflo(uA.w); accB.w += eA * bfhi(uA.w);
    accA.x += eB * bflo(uB.x); accA.y += eB * bfhi(uB.x);
    accA.z += eB * bflo(uB.y); accA.w += eB * bfhi(uB.y);
    accB.x += eB * bflo(uB.z); accB.y += eB * bfhi(uB.z);
    accB.z += eB * bflo(uB.w); accB.w += eB * bfhi(uB.w);
  }
  if (i <= deg) {   // at most one remaining edge per slot
    int s = (i < deg) ? col[start + i] : n;
    float e = __expf(lrelu(as1[s * 4 + head] + adh));
    uint4 u = *(const uint4*)(h1b + (size_t)s * F1 + lane16 * 8);
    dn += e;
    accA.x += e * bflo(u.x); accA.y += e * bfhi(u.x);
    accA.z += e * bflo(u.y); accA.w += e * bfhi(u.y);
    accB.x += e * bflo(u.z); accB.y += e * bfhi(u.z);
    accB.z += e * bflo(u.w); accB.w += e * bfhi(u.w);
  }
  // cross-slot reduce: slot bits are lane bits 4,5 (xor butterfly); dn is 9th value
#pragma unroll
  for (int off = 16; off <= 32; off <<= 1) {
    accA.x += __shfl_xor(accA.x, off); accA.y += __shfl_xor(accA.y, off);
    accA.z += __shfl_xor(accA.z, off); accA.w += __shfl_xor(accA.w, off);
    accB.x += __shfl_xor(accB.x, off); accB.y += __shfl_xor(accB.y, off);
    accB.z += __shfl_xor(accB.z, off); accB.w += __shfl_xor(accB.w, off);
    dn += __shfl_xor(dn, off);
  }
  if (slot == 0) {
    float rsh = 1.f / (dn + 1e-16f);
    float4 bA = *(const float4*)&b1[lane16 * 8];
    float4 bB = *(const float4*)&b1[lane16 * 8 + 4];
    float o[8];
    o[0] = fmaxf(accA.x * rsh + bA.x, 0.f); o[1] = fmaxf(accA.y * rsh + bA.y, 0.f);
    o[2] = fmaxf(accA.z * rsh + bA.z, 0.f); o[3] = fmaxf(accA.w * rsh + bA.w, 0.f);
    o[4] = fmaxf(accB.x * rsh + bB.x, 0.f); o[5] = fmaxf(accB.y * rsh + bB.y, 0.f);
    o[6] = fmaxf(accB.z * rsh + bB.z, 0.f); o[7] = fmaxf(accB.w * rsh + bB.w, 0.f);
    unsigned int hw[4], lw[4];
#pragma unroll
    for (int p = 0; p < 4; p++) {
      unsigned short h0 = f2bf(o[2 * p]);
      unsigned short h1 = f2bf(o[2 * p + 1]);
      unsigned short l0 = f2bf(o[2 * p] - bf2f(h0));
      unsigned short l1 = f2bf(o[2 * p + 1] - bf2f(h1));
      hw[p] = (unsigned int)h0 | ((unsigned int)h1 << 16);
      lw[p] = (unsigned int)l0 | ((unsigned int)l1 << 16);
    }
    *(uint4*)&x2h[(size_t)n * F1 + lane16 * 8] = make_uint4(hw[0], hw[1], hw[2], hw[3]);
    *(uint4*)&x2l[(size_t)n * F1 + lane16 * 8] = make_uint4(lw[0], lw[1], lw[2], lw[3]);
  }
}

// ---------------- GEMM2 via MFMA (R9): h2b = x2@W2 (bf16 split), as2/ad2 fused ----------
// Old version: 10 scalar ds_read_b32 per thread per k (1408 LDS insts/wave) + 55.8KB
// LDS (2 blocks/CU) -> ~27us of LDS issue. New: zero LDS, 36 MFMAs/wave, gemm1-style
// epilogue. Split-bf16 3-term ~1e-4 rel error, far under the bf16-dominated margin.
__global__ __launch_bounds__(256) void gemm2_kernel(
    const unsigned short* __restrict__ x2h, const unsigned short* __restrict__ x2l,
    const unsigned short* __restrict__ w2h, const unsigned short* __restrict__ w2l,
    const float* __restrict__ a2s, const float* __restrict__ a2d,
    unsigned short* __restrict__ h2b, float* __restrict__ as2, float* __restrict__ ad2) {
  int tid = threadIdx.x;
  int w = tid >> 6;
  int lane = tid & 63;
  int q = lane >> 4;
  int ln = lane & 15;
  int rowBase = blockIdx.x * 64 + w * 16;
  int rowA = rowBase + ln;
  int rowAc = rowA < N_NODES ? rowA : N_NODES - 1;
  float4v acc[3];
#pragma unroll
  for (int t = 0; t < 3; t++) acc[t] = (float4v){0.f, 0.f, 0.f, 0.f};
  const short8* ahp = (const short8*)(x2h + (size_t)rowAc * F1);
  const short8* alp = (const short8*)(x2l + (size_t)rowAc * F1);
  const short8* bhp = (const short8*)w2h;
  const short8* blp = (const short8*)w2l;
#pragma unroll
  for (int kk = 0; kk < 4; kk++) {
    short8 ahi = ahp[kk * 4 + q];
    short8 alo = alp[kk * 4 + q];
#pragma unroll
    for (int t = 0; t < 3; t++) {
      short8 bh = bhp[(kk * 3 + t) * 64 + lane];
      short8 bl = blp[(kk * 3 + t) * 64 + lane];
      acc[t] = __builtin_amdgcn_mfma_f32_16x16x32_bf16(ahi, bh, acc[t], 0, 0, 0);
      acc[t] = __builtin_amdgcn_mfma_f32_16x16x32_bf16(ahi, bl, acc[t], 0, 0, 0);
      acc[t] = __builtin_amdgcn_mfma_f32_16x16x32_bf16(alo, bh, acc[t], 0, 0, 0);
    }
  }
  float a2sv[3], a2dv[3];
#pragma unroll
  for (int t = 0; t < 3; t++) {
    int n = t * 16 + ln;
    a2sv[t] = (n < OUT_DIM) ? a2s[n] : 0.f;
    a2dv[t] = (n < OUT_DIM) ? a2d[n] : 0.f;
  }
#pragma unroll
  for (int reg = 0; reg < 4; reg++) {
    int r = rowBase + q * 4 + reg;
    bool valid = (r < N_NODES);
    float sa = acc[0][reg] * a2sv[0] + acc[1][reg] * a2sv[1] + acc[2][reg] * a2sv[2];
    float sd = acc[0][reg] * a2dv[0] + acc[1][reg] * a2dv[1] + acc[2][reg] * a2dv[2];
#pragma unroll
    for (int off = 1; off < 16; off <<= 1) {
      sa += __shfl_xor(sa, off);
      sd += __shfl_xor(sd, off);
    }
    if (valid) {
#pragma unroll
      for (int t = 0; t < 3; t++) {
        int n = t * 16 + ln;
        if (n < OUT_DIM) h2b[(size_t)r * OUT_DIM + n] = f2bf(acc[t][reg]);
      }
      if (ln == 0) { as2[r] = sa; ad2[r] = sd; }
    }
  }
}

// ---------------- layer-2: single-pass gather + log_softmax, 2-way ILP (R8) ----------------
__global__ __launch_bounds__(256) void gather2_kernel(
    const unsigned short* __restrict__ h2b, const float* __restrict__ as2,
    const float* __restrict__ ad2, const float* __restrict__ b2,
    const int* __restrict__ row_ptr, const int* __restrict__ col,
    float* __restrict__ out) {
  int wv = threadIdx.x >> 6;
  int n = blockIdx.x * 4 + wv;
  if (n >= N_NODES) return;
  int lane = threadIdx.x & 63;
  int start = row_ptr[n];
  int deg = row_ptr[n + 1] - start;
  float adh = ad2[n];
  // 12 slots x 5 lanes (16B bf16x8, row=80B); lanes 60..63 idle
  int slot = lane / 5;
  int c = lane - slot * 5;
  float4 accA = make_float4(0.f, 0.f, 0.f, 0.f);
  float4 accB = make_float4(0.f, 0.f, 0.f, 0.f);
  float dn = 0.f;
  if (slot < 12) {
    int i = slot;
    for (; i + 12 <= deg; i += 24) {
      int sA = col[start + i];
      int sB = (i + 12 < deg) ? col[start + i + 12] : n;
      float eA = __expf(lrelu(as2[sA] + adh));
      float eB = __expf(lrelu(as2[sB] + adh));
      uint4 uA = *(const uint4*)(h2b + (size_t)sA * OUT_DIM + c * 8);
      uint4 uB = *(const uint4*)(h2b + (size_t)sB * OUT_DIM + c * 8);
      dn += eA + eB;
      accA.x += eA * bflo(uA.x); accA.y += eA * bfhi(uA.x);
      accA.z += eA * bflo(uA.y); accA.w += eA * bfhi(uA.y);
      accB.x += eA * bflo(uA.z); accB.y += eA * bfhi(uA.z);
      accB.z += eA * bflo(uA.w); accB.w += eA * bfhi(uA.w);
      accA.x += eB * bflo(uB.x); accA.y += eB * bfhi(uB.x);
      accA.z += eB * bflo(uB.y); accA.w += eB * bfhi(uB.y);
      accB.x += eB * bflo(uB.z); accB.y += eB * bfhi(uB.z);
      accB.z += eB * bflo(uB.w); accB.w += eB * bfhi(uB.w);
    }
    if (i <= deg) {
      int src = (i < deg) ? col[start + i] : n;
      float e = __expf(lrelu(as2[src] + adh));
      uint4 u = *(const uint4*)(h2b + (size_t)src * OUT_DIM + c * 8);
      dn += e;
      accA.x += e * bflo(u.x); accA.y += e * bfhi(u.x);
      accA.z += e * bflo(u.y); accA.w += e * bfhi(u.y);
      accB.x += e * bflo(u.z); accB.y += e * bfhi(u.z);
      accB.z += e * bflo(u.w); accB.w += e * bfhi(u.w);
    }
  }
  // cross-slot reduce (12 slots); temps read before update; dn is v[8]
  float v[9] = {accA.x, accA.y, accA.z, accA.w, accB.x, accB.y, accB.z, accB.w, dn};
#pragma unroll
  for (int k = 0; k < 9; k++) v[k] += __shfl(v[k], lane + 30);
#pragma unroll
  for (int k = 0; k < 9; k++) v[k] += __shfl(v[k], lane + 15);
  {
    float t1[9], t2[9];
#pragma unroll
    for (int k = 0; k < 9; k++) t1[k] = __shfl(v[k], lane + 5);
#pragma unroll
    for (int k = 0; k < 9; k++) t2[k] = __shfl(v[k], lane + 10);
#pragma unroll
    for (int k = 0; k < 9; k++) v[k] += t1[k] + t2[k];
  }
  bool owner = (slot == 0);
  float vals[8];
  float lmax = -1e30f, lsum = 0.f;
  if (owner) {
    float rs = 1.f / (v[8] + 1e-16f);
#pragma unroll
    for (int k = 0; k < 8; k++) {
      vals[k] = v[k] * rs + b2[c * 8 + k];
      lmax = fmaxf(lmax, vals[k]);
    }
  }
  float gmax = lmax;
#pragma unroll
  for (int off = 32; off > 0; off >>= 1) gmax = fmaxf(gmax, __shfl_xor(gmax, off));
  if (owner) {
#pragma unroll
    for (int k = 0; k < 8; k++) lsum += __expf(vals[k] - gmax);
  }
#pragma unroll
  for (int off = 32; off > 0; off >>= 1) lsum += __shfl_xor(lsum, off);
  if (owner) {
    float lse = gmax + __logf(lsum);
    float4 oA = make_float4(vals[0] - lse, vals[1] - lse, vals[2] - lse, vals[3] - lse);
    float4 oB = make_float4(vals[4] - lse, vals[5] - lse, vals[6] - lse, vals[7] - lse);
    *(float4*)&out[(size_t)n * OUT_DIM + c * 8] = oA;
    *(float4*)&out[(size_t)n * OUT_DIM + c * 8 + 4] = oB;
  }
}

extern "C" void kernel_launch(void* const* d_in, const int* in_sizes, int n_in,
                              void* d_out, int out_size, void* d_ws, size_t ws_size,
                              hipStream_t stream) {
  const float* x      = (const float*)d_in[0];
  const int*   ei     = (const int*)d_in[1];
  const float* W1     = (const float*)d_in[2];
  const float* a_src1 = (const float*)d_in[3];
  const float* a_dst1 = (const float*)d_in[4];
  const float* b1     = (const float*)d_in[5];
  const float* W2     = (const float*)d_in[6];
  const float* a_src2 = (const float*)d_in[7];
  const float* a_dst2 = (const float*)d_in[8];
  const float* b2     = (const float*)d_in[9];
  float* out = (float*)d_out;

  char* ws = (char*)d_ws;
  size_t off = 0;
  auto alloc = [&](size_t bytes) -> void* {
    void* p = ws + off;
    off += (bytes + 255) & ~(size_t)255;
    return p;
  };
  unsigned short* h1b = (unsigned short*)alloc((size_t)N_NODES * F1 * 2);       // 12.8 MB
  unsigned short* h2b = (unsigned short*)alloc((size_t)N_NODES * OUT_DIM * 2);  // 4 MB
  unsigned short* wHi = (unsigned short*)alloc((size_t)IN_DIM * F1 * 2);        // 64 KB
  unsigned short* wLo = (unsigned short*)alloc((size_t)IN_DIM * F1 * 2);        // 64 KB
  unsigned short* w2h = (unsigned short*)alloc((size_t)768 * 8 * 2);            // 12 KB
  unsigned short* w2l = (unsigned short*)alloc((size_t)768 * 8 * 2);            // 12 KB
  float* as1    = (float*)alloc((size_t)N_NODES * HEADS * 4);
  float* ad1    = (float*)alloc((size_t)N_NODES * HEADS * 4);
  unsigned short* x2h = (unsigned short*)alloc((size_t)N_NODES * F1 * 2);       // 12.8 MB
  unsigned short* x2l = (unsigned short*)alloc((size_t)N_NODES * F1 * 2);       // 12.8 MB
  float* as2    = (float*)alloc((size_t)N_NODES * 4);
  float* ad2    = (float*)alloc((size_t)N_NODES * 4);
  int* row_ptr  = (int*)alloc((size_t)(N_NODES + 1) * 4);
  int* col      = (int*)alloc((size_t)N_EDGES * 4);
  int* gcnt     = (int*)alloc((size_t)NB * 4);
  int2* gbucket = (int2*)alloc((size_t)NB * CAP * 8);                           // 9.6 MB

  hipMemsetAsync(gcnt, 0, (size_t)NB * 4, stream);
  // pre: w1pack (16) U w2pack (3) U bin (196)
  pre_kernel<<<PREW + W2PB + (N_EDGES + EB - 1) / EB, 256, 0, stream>>>(
      W1, wHi, wLo, W2, w2h, w2l, ei, gcnt, gbucket);
  // mid: gemm1 (782 blocks) U csr-with-inline-scan (391 blocks)
  mid_kernel<<<G1B + NB, 256, 0, stream>>>(x, wHi, wLo, a_src1, a_dst1, h1b, as1, ad1,
                                           gbucket, gcnt, row_ptr, col);
  gather1_kernel<<<(N_NODES + 3) / 4, 256, 0, stream>>>(h1b, as1, ad1, b1, row_ptr, col,
                                                        x2h, x2l);
  gemm2_kernel<<<(N_NODES + 63) / 64, 256, 0, stream>>>(x2h, x2l, w2h, w2l,
                                                        a_src2, a_dst2, h2b, as2, ad2);
  gather2_kernel<<<(N_NODES + 3) / 4, 256, 0, stream>>>(h2b, as2, ad2, b2, row_ptr, col, out);
}